// Round 8
// baseline (541.955 us; speedup 1.0000x reference)
//
#include <hip/hip_runtime.h>
#include <hip/hip_fp16.h>

#define NN 65536
#define EE 524288
#define CC 128
#define CAP 32   // max in-degree bucket; P(deg>32) ~ 2e-11 per node at lambda=8 (guarded anyway)
#define RPB 64   // rows per k_layer block: grid = NN/RPB = 1024 -> 4 blocks/CU
#define NBUCK 8  // pstat atomic buckets (blockIdx & 7) to cap global-atomic contention

typedef _Float16 f16x8 __attribute__((ext_vector_type(8)));
typedef float f32x4 __attribute__((ext_vector_type(4)));

// ---------- phase 0: convert + stats (blocks 0..255) | bucket scatter (blocks 256..767) ----------

__global__ void k_init(const float* __restrict__ x, __half* __restrict__ h,
                       float* __restrict__ pstat0,
                       const int* __restrict__ src, const int* __restrict__ dst,
                       const float* __restrict__ ew,
                       int* __restrict__ cnt, unsigned int* __restrict__ buf) {
    int b = blockIdx.x, t = threadIdx.x;
    if (b < 256) {
        // fp32 -> fp16 convert + layer-0 BN stats on fp32 values
        const float4* xv = (const float4*)x;
        __half2* o = (__half2*)h;
        float s[4] = {0, 0, 0, 0}, q[4] = {0, 0, 0, 0};
        for (int k = 0; k < 32; k++) {
            int i = b * 8192 + k * 256 + t;
            float4 v = xv[i];
            o[2 * i]     = __floats2half2_rn(v.x, v.y);
            o[2 * i + 1] = __floats2half2_rn(v.z, v.w);
            s[0] += v.x; s[1] += v.y; s[2] += v.z; s[3] += v.w;
            q[0] += v.x * v.x; q[1] += v.y * v.y; q[2] += v.z * v.z; q[3] += v.w * v.w;
        }
        __shared__ float ls[256];          // [0..127] sum, [128..255] sumsq
        ls[t] = 0.f;
        __syncthreads();
        int c0 = (t & 31) * 4;
#pragma unroll
        for (int u = 0; u < 4; u++) {
            atomicAdd(&ls[c0 + u], s[u]);
            atomicAdd(&ls[128 + c0 + u], q[u]);
        }
        __syncthreads();
        if (t < 128) {                     // layer-0 stats land in bucket 0
            atomicAdd(&pstat0[t], ls[t]);
            atomicAdd(&pstat0[128 + t], ls[128 + t]);
        }
    } else {
        // bucket-CSR build: 4 edges per thread, loads/atomics/stores batched per class
        int base = (b - 256) * 1024 + t;
        int dd[4], sr[4];
        float we[4];
#pragma unroll
        for (int u = 0; u < 4; u++) dd[u] = dst[base + u * 256];
#pragma unroll
        for (int u = 0; u < 4; u++) sr[u] = src[base + u * 256];
#pragma unroll
        for (int u = 0; u < 4; u++) we[u] = ew[base + u * 256];
        int pos[4];
#pragma unroll
        for (int u = 0; u < 4; u++) pos[u] = atomicAdd(&cnt[dd[u]], 1);
#pragma unroll
        for (int u = 0; u < 4; u++) {
            float w = log1pf(we[u]);
            unsigned int pk = (unsigned int)sr[u] |
                              ((unsigned int)__half_as_ushort(__float2half(w)) << 16);
            if (pos[u] < CAP) buf[dd[u] * CAP + pos[u]] = pk;   // guard: never corrupt memory
        }
    }
}

// ---------- per-layer BN-fold: Wcat = alpha*W (fp16), crow/cneigh rank-1 corrections ----------
// pstat_l: [NBUCK][256] partial sums -> reduce buckets here.

__global__ void k_fold(const float* __restrict__ pstat_l,
                       const float* __restrict__ gamma, const float* __restrict__ beta,
                       const float* __restrict__ Ws, const float* __restrict__ Wn,
                       const float* __restrict__ bias,
                       __half* __restrict__ Wcat, float* __restrict__ crow,
                       float* __restrict__ cneigh) {
    int bid = blockIdx.x;
    int tid = threadIdx.x;
    int c = bid * 2 + (tid >> 7);
    int k = tid & 127;
    float su = 0.f, sq = 0.f;
#pragma unroll
    for (int b = 0; b < NBUCK; b++) {
        su += pstat_l[b * 256 + k];
        sq += pstat_l[b * 256 + 128 + k];
    }
    float mu = su * (1.0f / NN);
    float var = sq * (1.0f / NN) - mu * mu;
    float alpha = rsqrtf(var + 1e-5f) * gamma[k];
    float delta = beta[k] - mu * alpha;
    float ws = Ws[k * 128 + c];
    float wn = Wn[k * 128 + c];
    Wcat[c * 256 + k]       = __float2half(alpha * ws);   // self path
    Wcat[c * 256 + 128 + k] = __float2half(alpha * wn);   // neigh path
    float rs = delta * ws, rn = delta * wn;
#pragma unroll
    for (int off = 1; off < 64; off <<= 1) {
        rs += __shfl_xor(rs, off);
        rn += __shfl_xor(rn, off);
    }
    __shared__ float tmp[8];
    int wv = tid >> 6;                 // wave 0..3
    if ((tid & 63) == 0) { tmp[wv * 2] = rs; tmp[wv * 2 + 1] = rn; }
    __syncthreads();
    if ((tid & 127) == 0) {            // tid 0 (c lower) and 128 (c upper)
        int base = (tid >> 7) * 4;
        crow[c]   = bias[c] + tmp[base + 0] + tmp[base + 2];
        cneigh[c] = tmp[base + 1] + tmp[base + 3];
    }
}

// ---------- fused layer: 64 rows/block (4 waves x 16-row strips), grid 1024 ----------
// PAIRED-GROUP PIPELINED GATHER: quarter-wave owns a row, lane owns 8 channels (fp32
// private acc). Row-groups processed in PAIRS: both groups' 8-load bursts are issued
// before either group's FMAs -> ~16 gathers in flight per wave (2x R7). Invalid edge
// slots clamp to row 0 (L1-hot) with packed weight 0. No cross-lane reduction.
// Barrier-free main body; B (Wcat) straight from global (L1/L2-resident).
// mode 0: write h_next + BN stats (bucketed). mode 1: dot lin_w -> outv.
__launch_bounds__(256, 4)
__global__ void k_layer(const __half* __restrict__ hin,
                        const int* __restrict__ cnt,
                        const unsigned int* __restrict__ buf,
                        const __half* __restrict__ Wcat,
                        const float* __restrict__ crow, const float* __restrict__ cneigh,
                        float* __restrict__ sod, int writeSod,
                        const float* __restrict__ lin_w, const float* __restrict__ lin_b,
                        __half* __restrict__ hout, float* __restrict__ outv, int mode,
                        float* __restrict__ pstatN) {
    __shared__ __half aggT[RPB * 136];   // aggregated neigh rows [row_local][k], per-wave regions
    __shared__ float sodT[RPB];
    int tid = threadIdx.x;
    int lane = tid & 63;
    int wvid = tid >> 6;                 // wave 0..3 -> rows [wvid*16, wvid*16+16)
    int l15 = lane & 15, quad = lane >> 4;
    int i0 = blockIdx.x * RPB;
    int rbase = i0 + wvid * 16;

    // ---- prefetch self-strip A fragments (consumed after the gather phase) ----
    f16x8 as0[4];
#pragma unroll
    for (int s = 0; s < 4; s++) {
        int kof = s * 32 + quad * 8;
        as0[s] = *(const f16x8*)&hin[(rbase + l15) * 128 + kof];
    }

    // ---- aggregation: quarter-wave per row, 4 row-groups in 2 pipelined pairs ----
    const f16x8* hv = (const f16x8*)hin;   // row n = indices [n*16 .. n*16+15]
    int dv = cnt[rbase + l15]; if (dv > CAP) dv = CAP;   // degree of row rbase+(lane&15)
    unsigned int pkg0, pkg1, pkg2, pkg3;   // entries 0..15 of each group's own row
    pkg0 = buf[(rbase + 0 * 4 + quad) * CAP + l15];
    pkg1 = buf[(rbase + 1 * 4 + quad) * CAP + l15];
    pkg2 = buf[(rbase + 2 * 4 + quad) * CAP + l15];
    pkg3 = buf[(rbase + 3 * 4 + quad) * CAP + l15];

#pragma unroll
    for (int pr = 0; pr < 2; pr++) {
        int ga = pr * 2, gb = ga + 1;
        unsigned int pka = (pr == 0) ? pkg0 : pkg2;
        unsigned int pkb = (pr == 0) ? pkg1 : pkg3;
        int dqa = __shfl(dv, ga * 4 + quad);     // degree of quarter's row, group a
        int dqb = __shfl(dv, gb * 4 + quad);
        int t0 = __shfl_xor(dqa, 16); int dma = dqa > t0 ? dqa : t0;
        t0 = __shfl_xor(dma, 32); dma = dma > t0 ? dma : t0;   // wave-uniform max, group a
        int t1 = __shfl_xor(dqb, 16); int dmb = dqb > t1 ? dqb : t1;
        t1 = __shfl_xor(dmb, 32); dmb = dmb > t1 ? dmb : t1;
        unsigned int pk2a = 0, pk2b = 0;
        if (dma > 16) pk2a = buf[(rbase + ga * 4 + quad) * CAP + 16 + l15];
        if (dmb > 16) pk2b = buf[(rbase + gb * 4 + quad) * CAP + 16 + l15];
        float acca[8], accb[8];
#pragma unroll
        for (int u = 0; u < 8; u++) { acca[u] = 0.f; accb[u] = 0.f; }
        int ncha = (dma + 7) >> 3, nchb = (dmb + 7) >> 3;
        int nch = ncha > nchb ? ncha : nchb;
        for (int c = 0; c < nch; ++c) {
            int sbase = (quad << 4) + ((c & 1) << 3);
            int e0 = c * 8;
            bool da = (c < ncha), db = (c < nchb);
            unsigned int pea[8], peb[8];
            f16x8 vea[8], veb[8];
            // issue BOTH groups' load bursts before any FMA
            if (da) {
                unsigned int sa = (c & 2) ? pk2a : pka;
#pragma unroll
                for (int e = 0; e < 8; e++) pea[e] = __shfl(sa, sbase + e);
#pragma unroll
                for (int e = 0; e < 8; e++) if (e0 + e >= dqa) pea[e] = 0;  // row0, w=+0
#pragma unroll
                for (int e = 0; e < 8; e++) vea[e] = hv[(pea[e] & 0xFFFF) * 16 + l15];
            }
            if (db) {
                unsigned int sb = (c & 2) ? pk2b : pkb;
#pragma unroll
                for (int e = 0; e < 8; e++) peb[e] = __shfl(sb, sbase + e);
#pragma unroll
                for (int e = 0; e < 8; e++) if (e0 + e >= dqb) peb[e] = 0;
#pragma unroll
                for (int e = 0; e < 8; e++) veb[e] = hv[(peb[e] & 0xFFFF) * 16 + l15];
            }
            if (da) {
#pragma unroll
                for (int e = 0; e < 8; e++) {
                    float w = __half2float(__ushort_as_half((unsigned short)(pea[e] >> 16)));
#pragma unroll
                    for (int u = 0; u < 8; u++) acca[u] += w * (float)vea[e][u];
                }
            }
            if (db) {
#pragma unroll
                for (int e = 0; e < 8; e++) {
                    float w = __half2float(__ushort_as_half((unsigned short)(peb[e] >> 16)));
#pragma unroll
                    for (int u = 0; u < 8; u++) accb[u] += w * (float)veb[e][u];
                }
            }
        }
        float inva = 1.0f / (float)(dqa > 1 ? dqa : 1);
        float invb = 1.0f / (float)(dqb > 1 ? dqb : 1);
        int rla = wvid * 16 + ga * 4 + quad;
        int rlb = wvid * 16 + gb * 4 + quad;
        f16x8 oa, ob;
#pragma unroll
        for (int u = 0; u < 8; u++) oa[u] = (_Float16)(acca[u] * inva);
#pragma unroll
        for (int u = 0; u < 8; u++) ob[u] = (_Float16)(accb[u] * invb);
        *(f16x8*)&aggT[rla * 136 + l15 * 8] = oa;
        *(f16x8*)&aggT[rlb * 136 + l15 * 8] = ob;
        if (writeSod) {
            float wsa = (l15 < dqa)
                ? __half2float(__ushort_as_half((unsigned short)(pka >> 16))) : 0.f;
            if (16 + l15 < dqa)
                wsa += __half2float(__ushort_as_half((unsigned short)(pk2a >> 16)));
            float wsb = (l15 < dqb)
                ? __half2float(__ushort_as_half((unsigned short)(pkb >> 16))) : 0.f;
            if (16 + l15 < dqb)
                wsb += __half2float(__ushort_as_half((unsigned short)(pk2b >> 16)));
#pragma unroll
            for (int off = 1; off < 16; off <<= 1) {
                wsa += __shfl_xor(wsa, off);
                wsb += __shfl_xor(wsb, off);
            }
            if (l15 == 0) {
                sodT[rla] = wsa * inva; sod[i0 + rla] = wsa * inva;
                sodT[rlb] = wsb * invb; sod[i0 + rlb] = wsb * invb;
            }
        }
    }

    // ---- GEMM: chunk 0 (self, A in regs) then chunk 1 (neigh, A from aggT), B from global ----
    f32x4 acc[8];
    f32x4 zero = {0.f, 0.f, 0.f, 0.f};
#pragma unroll
    for (int t = 0; t < 8; t++) acc[t] = zero;

#pragma unroll
    for (int s = 0; s < 4; s++) {
        int kof = s * 32 + quad * 8;
#pragma unroll
        for (int tn = 0; tn < 8; tn++) {
            f16x8 bf = *(const f16x8*)&Wcat[(tn * 16 + l15) * 256 + kof];
            acc[tn] = __builtin_amdgcn_mfma_f32_16x16x32_f16(as0[s], bf, acc[tn], 0, 0, 0);
        }
    }
#pragma unroll
    for (int s = 0; s < 4; s++) {
        int kof = s * 32 + quad * 8;
        f16x8 an0 = *(const f16x8*)&aggT[(wvid * 16 + l15) * 136 + kof];
#pragma unroll
        for (int tn = 0; tn < 8; tn++) {
            f16x8 bf = *(const f16x8*)&Wcat[(tn * 16 + l15) * 256 + 128 + kof];
            acc[tn] = __builtin_amdgcn_mfma_f32_16x16x32_f16(an0, bf, acc[tn], 0, 0, 0);
        }
    }

    float cr[8], cn[8];
#pragma unroll
    for (int tn = 0; tn < 8; tn++) {
        cr[tn] = crow[tn * 16 + l15];
        cn[tn] = cneigh[tn * 16 + l15];
    }
    int rwbase = i0 + wvid * 16 + quad * 4;

    if (mode == 0) {
        float cs[8], cq[8];
#pragma unroll
        for (int tn = 0; tn < 8; tn++) { cs[tn] = 0.f; cq[tn] = 0.f; }
#pragma unroll
        for (int r = 0; r < 4; r++) {
            int row = rwbase + r;
            float sdv = writeSod ? sodT[row - i0] : sod[row];
#pragma unroll
            for (int tn = 0; tn < 8; tn++) {
                float v = acc[tn][r] + cr[tn] + sdv * cn[tn];
                v = fmaxf(v, 0.f);
                hout[row * 128 + tn * 16 + l15] = __float2half(v);
                cs[tn] += v;
                cq[tn] += v * v;
            }
        }
        // reduce stats across quads within wave, then LDS across waves, then global (bucketed)
#pragma unroll
        for (int tn = 0; tn < 8; tn++) {
            cs[tn] += __shfl_xor(cs[tn], 16); cs[tn] += __shfl_xor(cs[tn], 32);
            cq[tn] += __shfl_xor(cq[tn], 16); cq[tn] += __shfl_xor(cq[tn], 32);
        }
        float* st = (float*)aggT;          // reuse LDS: [0..127] sum, [128..255] sumsq
        __syncthreads();                   // all waves done reading aggT
        st[tid] = 0.f;
        __syncthreads();
        if (lane < 16) {
#pragma unroll
            for (int tn = 0; tn < 8; tn++) {
                atomicAdd(&st[tn * 16 + l15], cs[tn]);
                atomicAdd(&st[128 + tn * 16 + l15], cq[tn]);
            }
        }
        __syncthreads();
        if (tid < 128) {
            float* pb = pstatN + ((blockIdx.x & (NBUCK - 1)) << 8);
            atomicAdd(&pb[tid], st[tid]);
            atomicAdd(&pb[128 + tid], st[128 + tid]);
        }
    } else {
        float lw[8];
#pragma unroll
        for (int tn = 0; tn < 8; tn++) lw[tn] = lin_w[tn * 16 + l15];
        float lb = lin_b[0];
#pragma unroll
        for (int r = 0; r < 4; r++) {
            int row = rwbase + r;
            float sdv = sod[row];
            float p = 0.f;
#pragma unroll
            for (int tn = 0; tn < 8; tn++) {
                float v = acc[tn][r] + cr[tn] + sdv * cn[tn];
                v = fmaxf(v, 0.f);
                p += v * lw[tn];
            }
            p += __shfl_xor(p, 1);
            p += __shfl_xor(p, 2);
            p += __shfl_xor(p, 4);
            p += __shfl_xor(p, 8);
            if (l15 == 0) outv[row] = p + lb;
        }
    }
}

// ---------- host ----------

extern "C" void kernel_launch(void* const* d_in, const int* in_sizes, int n_in,
                              void* d_out, int out_size, void* d_ws, size_t ws_size,
                              hipStream_t stream) {
    (void)in_sizes; (void)n_in; (void)out_size; (void)ws_size;
    const float* x     = (const float*)d_in[0];
    const float* ew    = (const float*)d_in[1];
    const float* gamma = (const float*)d_in[2];
    const float* beta  = (const float*)d_in[3];
    const float* Ws    = (const float*)d_in[4];
    const float* Wn    = (const float*)d_in[5];
    const float* bias  = (const float*)d_in[6];
    const float* lin_w = (const float*)d_in[7];
    const float* lin_b = (const float*)d_in[8];
    const int*   srcI  = (const int*)d_in[9];
    const int*   dstI  = (const int*)d_in[10];
    float* out = (float*)d_out;

    char* p = (char*)d_ws;
    __half* ha   = (__half*)p; p += (size_t)NN * CC * 2;   // ping
    __half* hb   = (__half*)p; p += (size_t)NN * CC * 2;   // pong
    __half* Wcat = (__half*)p; p += 256 * 128 * 2;
    float* crow   = (float*)p; p += 512;
    float* cneigh = (float*)p; p += 512;
    float* sod    = (float*)p; p += (size_t)NN * 4;
    unsigned int* buf = (unsigned int*)p; p += (size_t)NN * CAP * 4;
    // ---- contiguous zero region ----
    int*   cnt    = (int*)p;   p += (size_t)NN * 4;
    float* pstat  = (float*)p; p += 3 * NBUCK * 256 * 4;   // [layer][bucket][sum|sumsq]

    hipMemsetAsync(cnt, 0, (size_t)NN * 4 + 3 * NBUCK * 256 * 4, stream);

    k_init<<<dim3(256 + EE / 1024), dim3(256), 0, stream>>>(x, ha, pstat, srcI, dstI, ew, cnt, buf);

    const __half* hin = ha;
    __half* hout = hb;
    for (int l = 0; l < 3; l++) {
        k_fold<<<dim3(64), dim3(256), 0, stream>>>(
            pstat + (size_t)l * NBUCK * 256, gamma + l * CC, beta + l * CC,
            Ws + (size_t)l * CC * CC, Wn + (size_t)l * CC * CC, bias + l * CC,
            Wcat, crow, cneigh);
        int mode = (l == 2) ? 1 : 0;
        float* pstatN = (mode == 0) ? (pstat + (size_t)(l + 1) * NBUCK * 256) : pstat;
        k_layer<<<dim3(NN / RPB), dim3(256), 0, stream>>>(
            hin, cnt, buf, Wcat, crow, cneigh, sod, (l == 0) ? 1 : 0,
            lin_w, lin_b, hout, out, mode, pstatN);
        const __half* t = hin; hin = hout; hout = (__half*)t;
    }
}

// Round 9
// 325.983 us; speedup vs baseline: 1.6625x; 1.6625x over previous
//
#include <hip/hip_runtime.h>
#include <hip/hip_fp16.h>

#define NN 65536
#define EE 524288
#define CC 128
#define CAP 32   // max in-degree bucket; P(deg>32) ~ 2e-11 per node at lambda=8 (guarded anyway)
#define RPB 64   // rows per k_gemm block: grid = NN/RPB = 1024 -> 4 blocks/CU
#define NBUCK 8  // pstat atomic buckets (blockIdx & 7) to cap global-atomic contention

typedef _Float16 f16x8 __attribute__((ext_vector_type(8)));
typedef float f32x4 __attribute__((ext_vector_type(4)));

// ---------- phase 0: convert + stats (blocks 0..255) | bucket scatter (blocks 256..767) ----------

__global__ void k_init(const float* __restrict__ x, __half* __restrict__ h,
                       float* __restrict__ pstat0,
                       const int* __restrict__ src, const int* __restrict__ dst,
                       const float* __restrict__ ew,
                       int* __restrict__ cnt, unsigned int* __restrict__ buf) {
    int b = blockIdx.x, t = threadIdx.x;
    if (b < 256) {
        // fp32 -> fp16 convert + layer-0 BN stats on fp32 values
        const float4* xv = (const float4*)x;
        __half2* o = (__half2*)h;
        float s[4] = {0, 0, 0, 0}, q[4] = {0, 0, 0, 0};
        for (int k = 0; k < 32; k++) {
            int i = b * 8192 + k * 256 + t;
            float4 v = xv[i];
            o[2 * i]     = __floats2half2_rn(v.x, v.y);
            o[2 * i + 1] = __floats2half2_rn(v.z, v.w);
            s[0] += v.x; s[1] += v.y; s[2] += v.z; s[3] += v.w;
            q[0] += v.x * v.x; q[1] += v.y * v.y; q[2] += v.z * v.z; q[3] += v.w * v.w;
        }
        __shared__ float ls[256];          // [0..127] sum, [128..255] sumsq
        ls[t] = 0.f;
        __syncthreads();
        int c0 = (t & 31) * 4;
#pragma unroll
        for (int u = 0; u < 4; u++) {
            atomicAdd(&ls[c0 + u], s[u]);
            atomicAdd(&ls[128 + c0 + u], q[u]);
        }
        __syncthreads();
        if (t < 128) {                     // layer-0 stats land in bucket 0
            atomicAdd(&pstat0[t], ls[t]);
            atomicAdd(&pstat0[128 + t], ls[128 + t]);
        }
    } else {
        // bucket-CSR build: 4 edges per thread, loads/atomics/stores batched per class
        int base = (b - 256) * 1024 + t;
        int dd[4], sr[4];
        float we[4];
#pragma unroll
        for (int u = 0; u < 4; u++) dd[u] = dst[base + u * 256];
#pragma unroll
        for (int u = 0; u < 4; u++) sr[u] = src[base + u * 256];
#pragma unroll
        for (int u = 0; u < 4; u++) we[u] = ew[base + u * 256];
        int pos[4];
#pragma unroll
        for (int u = 0; u < 4; u++) pos[u] = atomicAdd(&cnt[dd[u]], 1);
#pragma unroll
        for (int u = 0; u < 4; u++) {
            float w = log1pf(we[u]);
            unsigned int pk = (unsigned int)sr[u] |
                              ((unsigned int)__half_as_ushort(__float2half(w)) << 16);
            if (pos[u] < CAP) buf[dd[u] * CAP + pos[u]] = pk;   // guard: never corrupt memory
        }
    }
}

// ---------- per-layer BN-fold: Wcat = alpha*W (fp16), crow/cneigh rank-1 corrections ----------
// pstat_l: [NBUCK][256] partial sums -> reduce buckets here.

__global__ void k_fold(const float* __restrict__ pstat_l,
                       const float* __restrict__ gamma, const float* __restrict__ beta,
                       const float* __restrict__ Ws, const float* __restrict__ Wn,
                       const float* __restrict__ bias,
                       __half* __restrict__ Wcat, float* __restrict__ crow,
                       float* __restrict__ cneigh) {
    int bid = blockIdx.x;
    int tid = threadIdx.x;
    int c = bid * 2 + (tid >> 7);
    int k = tid & 127;
    float su = 0.f, sq = 0.f;
#pragma unroll
    for (int b = 0; b < NBUCK; b++) {
        su += pstat_l[b * 256 + k];
        sq += pstat_l[b * 256 + 128 + k];
    }
    float mu = su * (1.0f / NN);
    float var = sq * (1.0f / NN) - mu * mu;
    float alpha = rsqrtf(var + 1e-5f) * gamma[k];
    float delta = beta[k] - mu * alpha;
    float ws = Ws[k * 128 + c];
    float wn = Wn[k * 128 + c];
    Wcat[c * 256 + k]       = __float2half(alpha * ws);   // self path
    Wcat[c * 256 + 128 + k] = __float2half(alpha * wn);   // neigh path
    float rs = delta * ws, rn = delta * wn;
#pragma unroll
    for (int off = 1; off < 64; off <<= 1) {
        rs += __shfl_xor(rs, off);
        rn += __shfl_xor(rn, off);
    }
    __shared__ float tmp[8];
    int wv = tid >> 6;                 // wave 0..3
    if ((tid & 63) == 0) { tmp[wv * 2] = rs; tmp[wv * 2 + 1] = rn; }
    __syncthreads();
    if ((tid & 127) == 0) {            // tid 0 (c lower) and 128 (c upper)
        int base = (tid >> 7) * 4;
        crow[c]   = bias[c] + tmp[base + 0] + tmp[base + 2];
        cneigh[c] = tmp[base + 1] + tmp[base + 3];
    }
}

// ---------- dedicated gather-aggregate: quarter-wave per node, pure gather, high occ ----------
// Every resident wave is gathering 100% of its lifetime with ~8 1KB loads in flight;
// ~55 VGPR -> 6 waves/SIMD resident (24 waves/CU). Lane owns 8 channels (16B), fp32
// private acc, no cross-lane reduce. Invalid slots -> row 0 (L1-hot), packed weight +0.
__launch_bounds__(256, 6)
__global__ void k_agg(const __half* __restrict__ hin,
                      const int* __restrict__ cnt,
                      const unsigned int* __restrict__ buf,
                      __half* __restrict__ aggn, float* __restrict__ sod, int writeSod) {
    int tid = threadIdx.x;
    int lane = tid & 63;
    int wvid = tid >> 6;
    int l15 = lane & 15, quad = lane >> 4;
    int n = blockIdx.x * 16 + wvid * 4 + quad;     // node owned by this quarter-wave
    const f16x8* hv = (const f16x8*)hin;           // row m = [m*16 .. m*16+15]

    int d = cnt[n]; if (d > CAP) d = CAP;
    unsigned int pk0 = 0, pk1 = 0;
    if (l15 < d) pk0 = buf[n * CAP + l15];
    int dm = d;
    { int t0 = __shfl_xor(dm, 16); dm = dm > t0 ? dm : t0; }
    { int t1 = __shfl_xor(dm, 32); dm = dm > t1 ? dm : t1; }   // wave-uniform max degree
    if (dm > 16 && 16 + l15 < d) pk1 = buf[n * CAP + 16 + l15];

    float acc[8];
#pragma unroll
    for (int u = 0; u < 8; u++) acc[u] = 0.f;
    int nch = (dm + 7) >> 3;                       // 1..4 chunks of 8 edges
    for (int c = 0; c < nch; ++c) {
        int sbase = (quad << 4) + ((c & 1) << 3);
        unsigned int sreg = (c & 2) ? pk1 : pk0;
        unsigned int pe[8];
        f16x8 ve[8];
#pragma unroll
        for (int e = 0; e < 8; e++) pe[e] = __shfl(sreg, sbase + e);
#pragma unroll
        for (int e = 0; e < 8; e++) ve[e] = hv[(pe[e] & 0xFFFF) * 16 + l15];
#pragma unroll
        for (int e = 0; e < 8; e++) {
            float w = __half2float(__ushort_as_half((unsigned short)(pe[e] >> 16)));
#pragma unroll
            for (int u = 0; u < 8; u++) acc[u] += w * (float)ve[e][u];
        }
    }
    float inv = 1.0f / (float)(d > 1 ? d : 1);
    f16x8 o;
#pragma unroll
    for (int u = 0; u < 8; u++) o[u] = (_Float16)(acc[u] * inv);
    *(f16x8*)&aggn[n * 128 + l15 * 8] = o;
    if (writeSod) {
        float ws = (l15 < d)
            ? __half2float(__ushort_as_half((unsigned short)(pk0 >> 16))) : 0.f;
        if (16 + l15 < d)
            ws += __half2float(__ushort_as_half((unsigned short)(pk1 >> 16)));
        ws += __shfl_xor(ws, 1); ws += __shfl_xor(ws, 2);
        ws += __shfl_xor(ws, 4); ws += __shfl_xor(ws, 8);
        if (l15 == 0) sod[n] = ws * inv;
    }
}

// ---------- dual-GEMM: relu([h | aggn] @ Wcat + crow + sod*cneigh), no LDS tiles ----------
// A-self prefetched to regs; A-neigh read from aggn (L2-warm, coalesced); B (Wcat)
// straight from global (L1/L2-resident). Barrier-free except the stats epilogue.
// mode 0: write h_next + BN stats (bucketed). mode 1: dot lin_w -> outv.
__launch_bounds__(256, 4)
__global__ void k_gemm(const __half* __restrict__ hin,
                       const __half* __restrict__ aggn,
                       const __half* __restrict__ Wcat,
                       const float* __restrict__ crow, const float* __restrict__ cneigh,
                       const float* __restrict__ sod,
                       const float* __restrict__ lin_w, const float* __restrict__ lin_b,
                       __half* __restrict__ hout, float* __restrict__ outv, int mode,
                       float* __restrict__ pstatN) {
    __shared__ float st[256];            // stats staging only
    int tid = threadIdx.x;
    int lane = tid & 63;
    int wvid = tid >> 6;                 // wave 0..3 -> rows [wvid*16, wvid*16+16)
    int l15 = lane & 15, quad = lane >> 4;
    int i0 = blockIdx.x * RPB;
    int rbase = i0 + wvid * 16;

    // prefetch both A-fragment sets (self from hin, neigh from aggn)
    f16x8 as0[4], an0[4];
#pragma unroll
    for (int s = 0; s < 4; s++) {
        int kof = s * 32 + quad * 8;
        as0[s] = *(const f16x8*)&hin[(rbase + l15) * 128 + kof];
        an0[s] = *(const f16x8*)&aggn[(rbase + l15) * 128 + kof];
    }

    f32x4 acc[8];
    f32x4 zero = {0.f, 0.f, 0.f, 0.f};
#pragma unroll
    for (int t = 0; t < 8; t++) acc[t] = zero;

#pragma unroll
    for (int s = 0; s < 4; s++) {
        int kof = s * 32 + quad * 8;
#pragma unroll
        for (int tn = 0; tn < 8; tn++) {
            f16x8 bf = *(const f16x8*)&Wcat[(tn * 16 + l15) * 256 + kof];
            acc[tn] = __builtin_amdgcn_mfma_f32_16x16x32_f16(as0[s], bf, acc[tn], 0, 0, 0);
        }
    }
#pragma unroll
    for (int s = 0; s < 4; s++) {
        int kof = s * 32 + quad * 8;
#pragma unroll
        for (int tn = 0; tn < 8; tn++) {
            f16x8 bf = *(const f16x8*)&Wcat[(tn * 16 + l15) * 256 + 128 + kof];
            acc[tn] = __builtin_amdgcn_mfma_f32_16x16x32_f16(an0[s], bf, acc[tn], 0, 0, 0);
        }
    }

    float cr[8], cn[8];
#pragma unroll
    for (int tn = 0; tn < 8; tn++) {
        cr[tn] = crow[tn * 16 + l15];
        cn[tn] = cneigh[tn * 16 + l15];
    }
    int rwbase = i0 + wvid * 16 + quad * 4;

    if (mode == 0) {
        float cs[8], cq[8];
#pragma unroll
        for (int tn = 0; tn < 8; tn++) { cs[tn] = 0.f; cq[tn] = 0.f; }
#pragma unroll
        for (int r = 0; r < 4; r++) {
            int row = rwbase + r;
            float sdv = sod[row];
#pragma unroll
            for (int tn = 0; tn < 8; tn++) {
                float v = acc[tn][r] + cr[tn] + sdv * cn[tn];
                v = fmaxf(v, 0.f);
                hout[row * 128 + tn * 16 + l15] = __float2half(v);
                cs[tn] += v;
                cq[tn] += v * v;
            }
        }
        // reduce stats across quads within wave, then LDS across waves, then global (bucketed)
#pragma unroll
        for (int tn = 0; tn < 8; tn++) {
            cs[tn] += __shfl_xor(cs[tn], 16); cs[tn] += __shfl_xor(cs[tn], 32);
            cq[tn] += __shfl_xor(cq[tn], 16); cq[tn] += __shfl_xor(cq[tn], 32);
        }
        st[tid] = 0.f;
        __syncthreads();
        if (lane < 16) {
#pragma unroll
            for (int tn = 0; tn < 8; tn++) {
                atomicAdd(&st[tn * 16 + l15], cs[tn]);
                atomicAdd(&st[128 + tn * 16 + l15], cq[tn]);
            }
        }
        __syncthreads();
        if (tid < 128) {
            float* pb = pstatN + ((blockIdx.x & (NBUCK - 1)) << 8);
            atomicAdd(&pb[tid], st[tid]);
            atomicAdd(&pb[128 + tid], st[128 + tid]);
        }
    } else {
        float lw[8];
#pragma unroll
        for (int tn = 0; tn < 8; tn++) lw[tn] = lin_w[tn * 16 + l15];
        float lb = lin_b[0];
#pragma unroll
        for (int r = 0; r < 4; r++) {
            int row = rwbase + r;
            float sdv = sod[row];
            float p = 0.f;
#pragma unroll
            for (int tn = 0; tn < 8; tn++) {
                float v = acc[tn][r] + cr[tn] + sdv * cn[tn];
                v = fmaxf(v, 0.f);
                p += v * lw[tn];
            }
            p += __shfl_xor(p, 1);
            p += __shfl_xor(p, 2);
            p += __shfl_xor(p, 4);
            p += __shfl_xor(p, 8);
            if (l15 == 0) outv[row] = p + lb;
        }
    }
}

// ---------- host ----------

extern "C" void kernel_launch(void* const* d_in, const int* in_sizes, int n_in,
                              void* d_out, int out_size, void* d_ws, size_t ws_size,
                              hipStream_t stream) {
    (void)in_sizes; (void)n_in; (void)out_size; (void)ws_size;
    const float* x     = (const float*)d_in[0];
    const float* ew    = (const float*)d_in[1];
    const float* gamma = (const float*)d_in[2];
    const float* beta  = (const float*)d_in[3];
    const float* Ws    = (const float*)d_in[4];
    const float* Wn    = (const float*)d_in[5];
    const float* bias  = (const float*)d_in[6];
    const float* lin_w = (const float*)d_in[7];
    const float* lin_b = (const float*)d_in[8];
    const int*   srcI  = (const int*)d_in[9];
    const int*   dstI  = (const int*)d_in[10];
    float* out = (float*)d_out;

    char* p = (char*)d_ws;
    __half* ha   = (__half*)p; p += (size_t)NN * CC * 2;   // ping
    __half* hb   = (__half*)p; p += (size_t)NN * CC * 2;   // pong
    __half* aggn = (__half*)p; p += (size_t)NN * CC * 2;   // aggregated neighbor rows
    __half* Wcat = (__half*)p; p += 256 * 128 * 2;
    float* crow   = (float*)p; p += 512;
    float* cneigh = (float*)p; p += 512;
    float* sod    = (float*)p; p += (size_t)NN * 4;
    unsigned int* buf = (unsigned int*)p; p += (size_t)NN * CAP * 4;
    // ---- contiguous zero region ----
    int*   cnt    = (int*)p;   p += (size_t)NN * 4;
    float* pstat  = (float*)p; p += 3 * NBUCK * 256 * 4;   // [layer][bucket][sum|sumsq]

    hipMemsetAsync(cnt, 0, (size_t)NN * 4 + 3 * NBUCK * 256 * 4, stream);

    k_init<<<dim3(256 + EE / 1024), dim3(256), 0, stream>>>(x, ha, pstat, srcI, dstI, ew, cnt, buf);

    const __half* hin = ha;
    __half* hout = hb;
    for (int l = 0; l < 3; l++) {
        k_fold<<<dim3(64), dim3(256), 0, stream>>>(
            pstat + (size_t)l * NBUCK * 256, gamma + l * CC, beta + l * CC,
            Ws + (size_t)l * CC * CC, Wn + (size_t)l * CC * CC, bias + l * CC,
            Wcat, crow, cneigh);
        k_agg<<<dim3(NN / 16), dim3(256), 0, stream>>>(
            hin, cnt, buf, aggn, sod, (l == 0) ? 1 : 0);
        int mode = (l == 2) ? 1 : 0;
        float* pstatN = (mode == 0) ? (pstat + (size_t)(l + 1) * NBUCK * 256) : pstat;
        k_gemm<<<dim3(NN / RPB), dim3(256), 0, stream>>>(
            hin, aggn, Wcat, crow, cneigh, sod,
            lin_w, lin_b, hout, out, mode, pstatN);
        const __half* t = hin; hin = hout; hout = (__half*)t;
    }
}